// Round 3
// baseline (1018.727 us; speedup 1.0000x reference)
//
#include <hip/hip_runtime.h>
#include <math.h>

// Problem constants
#define MROWS 2048      // BN*SN = 32*64
#define NCOLS 256       // NDF
#define KDIM  65536     // IN_DIM
#define NCLU  100

// ---- legacy (fallback) GEMM config ----
#define BM 128
#define BN 128
#define BK 32
#define SPLITK 16
#define KCHUNK (KDIM / SPLITK)   // 4096
#define SA 132
#define SB 128

// ---- MFMA GEMM config ----
#define BMT 128
#define BNT 128
#define BKT 32
#define NSTEP (KCHUNK / BKT)     // 128 k-steps per block
#define LDT 40                   // padded f16 LDS stride for A (80 B rows: 2-way max)
#define BTILE 16384              // bytes per B k-step tile: 128 n-rows x 128 B (hi|lo, XOR-swizzled)

typedef _Float16 half8  __attribute__((ext_vector_type(8)));
typedef _Float16 half4v __attribute__((ext_vector_type(4)));
typedef float    f32x4  __attribute__((ext_vector_type(4)));

// global_load_lds: LDS dest = wave-uniform base + lane*16 (linear); global src per-lane.
#define GLD_LDS16(g, l) __builtin_amdgcn_global_load_lds(                      \
    (__attribute__((address_space(1))) void*)(g),                              \
    (__attribute__((address_space(3))) void*)(l), 16, 0, 0)

// ------------------------------------------------------------------
// Prepass v2: B [K][256] fp32 -> swizzled-tiled hi/lo f16 stream.
// Stream = tiles T = ((bn*16 + ks)*128 + step), 16 KB each:
//   byte (n, x): logical lx = x ^ ((n&7)<<4); lx<64 -> hi half k=lx/2,
//   lx>=64 -> lo half k=(lx-64)/2   (k relative to the 32-wide k-step).
// gemm deposits tiles linearly via global_load_lds; swizzled ds_read_b128
// frag reads are then bank-conflict-free (2 lanes/16B-slot).
// ------------------------------------------------------------------
__global__ __launch_bounds__(256, 4)
void prep_b_kernel(const float* __restrict__ B, unsigned char* __restrict__ Bws)
{
    __shared__ float Ts[BKT][132];   // [k][n], +4 pad
    const int t    = threadIdx.x;
    const int step = blockIdx.x;
    const int ks   = blockIdx.y;
    const int bnb  = blockIdx.z;

    const int kbase = ks * KCHUNK + step * BKT;
    const int nbase = bnb * 128;

    #pragma unroll
    for (int r = 0; r < 4; ++r) {
        const int fidx = r * 256 + t;
        const int k  = fidx >> 5;        // 0..31
        const int c4 = fidx & 31;        // float4 col
        const float4 v = *(const float4*)(B + (size_t)(kbase + k) * NCOLS + nbase + c4 * 4);
        *(float4*)&Ts[k][c4 * 4] = v;
    }
    __syncthreads();

    unsigned char* outT = Bws + (size_t)((bnb * SPLITK + ks) * NSTEP + step) * BTILE;
    #pragma unroll
    for (int r = 0; r < 4; ++r) {
        const int oidx = r * 256 + t;
        const int n  = oidx >> 3;        // 0..127
        const int X  = oidx & 7;         // 16-B block within row
        const int LX = X ^ (n & 7);      // logical block
        const int mtx = LX >> 2;         // 0 = hi, 1 = lo
        const int kb  = (LX & 3) * 8;    // k offset of this 8-half block
        half8 hv;
        #pragma unroll
        for (int j = 0; j < 8; ++j) {
            const float v = Ts[kb + j][n];
            const _Float16 h = (_Float16)v;            // RNE
            hv[j] = mtx ? (_Float16)(v - (float)h) : h;
        }
        *(half8*)(outT + n * 128 + X * 16) = hv;       // coalesced: 8 lanes = 1 row
    }
}

// ------------------------------------------------------------------
// MFMA split-K GEMM v2: double-buffered, prefetch-ahead (T3 minimum 2-phase).
// A: reg-prefetch -> f16 cvt -> LDS (padded).  B: global_load_lds direct.
// ------------------------------------------------------------------
__global__ __launch_bounds__(256, 2)
void gemm_mfma_kernel(const float* __restrict__ A,
                      const unsigned char* __restrict__ Bws,
                      float* __restrict__ C)
{
    __shared__ _Float16 As[2][BMT][LDT];                 // 20.5 KB
    __shared__ __align__(16) unsigned char Bs[2][BTILE]; // 32 KB

    const int t    = threadIdx.x;
    const int lane = t & 63;
    const int wid  = t >> 6;
    const int wm   = wid >> 1;
    const int wn   = wid & 1;

    const int bm  = blockIdx.x;
    const int bnb = blockIdx.y;
    const int ks  = blockIdx.z;

    const float* Ab = A + (size_t)bm * BMT * KDIM + (size_t)ks * KCHUNK;
    const unsigned char* Bb = Bws + (size_t)((bnb * SPLITK + ks) * NSTEP) * BTILE;

    const int am  = t >> 3;          // A row 0..31 (+32/rep)
    const int akf = (t & 7) * 4;     // A float4 col

    const int r16  = lane & 15;
    const int kb16 = lane >> 4;      // k-block 0..3 (8 halves each)

    // B frag byte offsets within a tile (hi at logical bytes [0,64), lo [64,128))
    int bhoff[4], bloff[4];
    #pragma unroll
    for (int nf = 0; nf < 4; ++nf) {
        const int n    = wn * 64 + nf * 16 + r16;
        const int mask = (n & 7) << 4;
        bhoff[nf] = n * 128 + ((kb16 * 16) ^ mask);
        bloff[nf] = n * 128 + ((64 + kb16 * 16) ^ mask);
    }

    f32x4 acc[4][4] = {};
    float4 pA[4];

    // ---- prologue: stage step 0 into buffer 0 ----
    #pragma unroll
    for (int i = 0; i < 4; ++i)
        pA[i] = *(const float4*)(Ab + (size_t)(am + 32 * i) * KDIM + akf);
    #pragma unroll
    for (int r = 0; r < 4; ++r)
        GLD_LDS16(Bb + (size_t)(r * 256 + t) * 16,
                  &Bs[0][(r * 256 + wid * 64) * 16]);
    #pragma unroll
    for (int i = 0; i < 4; ++i) {
        half4v h;
        h[0] = (_Float16)pA[i].x; h[1] = (_Float16)pA[i].y;
        h[2] = (_Float16)pA[i].z; h[3] = (_Float16)pA[i].w;
        *(half4v*)&As[0][am + 32 * i][akf] = h;
    }
    __syncthreads();

    int cb = 0;
    for (int step = 0; step < NSTEP; ++step) {
        const int nb = cb ^ 1;
        const bool pf = (step + 1) < NSTEP;

        if (pf) {   // issue next-tile loads BEFORE compute (latency hides under MFMA)
            const int kk = (step + 1) * BKT;
            #pragma unroll
            for (int i = 0; i < 4; ++i)
                pA[i] = *(const float4*)(Ab + (size_t)(am + 32 * i) * KDIM + kk + akf);
            const unsigned char* Bt = Bb + (size_t)(step + 1) * BTILE;
            #pragma unroll
            for (int r = 0; r < 4; ++r)
                GLD_LDS16(Bt + (size_t)(r * 256 + t) * 16,
                          &Bs[nb][(r * 256 + wid * 64) * 16]);
        }

        half8 av[4], bh[4], bl[4];
        #pragma unroll
        for (int mf = 0; mf < 4; ++mf)
            av[mf] = *(const half8*)&As[cb][wm * 64 + mf * 16 + r16][kb16 * 8];
        #pragma unroll
        for (int nf = 0; nf < 4; ++nf) {
            bh[nf] = *(const half8*)&Bs[cb][bhoff[nf]];
            bl[nf] = *(const half8*)&Bs[cb][bloff[nf]];
        }
        #pragma unroll
        for (int mf = 0; mf < 4; ++mf)
            #pragma unroll
            for (int nf = 0; nf < 4; ++nf) {
                acc[mf][nf] = __builtin_amdgcn_mfma_f32_16x16x32_f16(av[mf], bh[nf], acc[mf][nf], 0, 0, 0);
                acc[mf][nf] = __builtin_amdgcn_mfma_f32_16x16x32_f16(av[mf], bl[nf], acc[mf][nf], 0, 0, 0);
            }

        if (pf) {   // finish A staging for next step (pA has arrived under MFMA)
            #pragma unroll
            for (int i = 0; i < 4; ++i) {
                half4v h;
                h[0] = (_Float16)pA[i].x; h[1] = (_Float16)pA[i].y;
                h[2] = (_Float16)pA[i].z; h[3] = (_Float16)pA[i].w;
                *(half4v*)&As[nb][am + 32 * i][akf] = h;
            }
        }
        __syncthreads();   // drains vmcnt(0): B gload_lds for next step complete
        cb = nb;
    }

    // epilogue: C/D layout col=lane&15, row=4*(lane>>4)+reg (m89-verified)
    const int row0 = bm * BMT + wm * 64 + (lane >> 4) * 4;
    const int col0 = bnb * BNT + wn * 64 + r16;
    #pragma unroll
    for (int mf = 0; mf < 4; ++mf)
        #pragma unroll
        for (int nf = 0; nf < 4; ++nf)
            #pragma unroll
            for (int r = 0; r < 4; ++r)
                atomicAdd(&C[(size_t)(row0 + mf * 16 + r) * NCOLS + col0 + nf * 16],
                          acc[mf][nf][r]);
}

// ------------------------------------------------------------------
// Fallback vector-FMA GEMM (verified baseline) — used only if ws too small
// ------------------------------------------------------------------
__global__ __launch_bounds__(256, 2)
void gemm_splitk_kernel(const float* __restrict__ A, const float* __restrict__ B,
                        float* __restrict__ C)
{
    __shared__ float As[BK][SA];
    __shared__ float Bs[BK][SB];

    const int t  = threadIdx.x;
    const int tx = t & 15;
    const int ty = t >> 4;

    const int bm = blockIdx.x;
    const int bn = blockIdx.y;
    const int bs = blockIdx.z;

    const float* Ab = A + (size_t)bm * BM * KDIM + (size_t)bs * KCHUNK;
    const float* Bb = B + (size_t)bs * KCHUNK * NCOLS + bn * BN;

    const int arow = t >> 3;
    const int akf4 = t & 7;
    const int bkr  = t >> 5;
    const int bnf4 = t & 31;

    float acc[8][8];
    #pragma unroll
    for (int i = 0; i < 8; ++i)
        #pragma unroll
        for (int j = 0; j < 8; ++j) acc[i][j] = 0.f;

    for (int kk = 0; kk < KCHUNK; kk += BK) {
        #pragma unroll
        for (int i = 0; i < 4; ++i) {
            const int r = arow + 32 * i;
            const float4 v = *(const float4*)(Ab + (size_t)r * KDIM + kk + akf4 * 4);
            As[akf4 * 4 + 0][r] = v.x;
            As[akf4 * 4 + 1][r] = v.y;
            As[akf4 * 4 + 2][r] = v.z;
            As[akf4 * 4 + 3][r] = v.w;
        }
        #pragma unroll
        for (int i = 0; i < 4; ++i) {
            const int r = bkr + 8 * i;
            *(float4*)&Bs[r][bnf4 * 4] =
                *(const float4*)(Bb + (size_t)(kk + r) * NCOLS + bnf4 * 4);
        }
        __syncthreads();

        #pragma unroll 8
        for (int k = 0; k < BK; ++k) {
            float a[8], b[8];
            *(float4*)&a[0] = *(const float4*)&As[k][ty * 4];
            *(float4*)&a[4] = *(const float4*)&As[k][64 + ty * 4];
            *(float4*)&b[0] = *(const float4*)&Bs[k][tx * 4];
            *(float4*)&b[4] = *(const float4*)&Bs[k][64 + tx * 4];
            #pragma unroll
            for (int i = 0; i < 8; ++i)
                #pragma unroll
                for (int j = 0; j < 8; ++j)
                    acc[i][j] = fmaf(a[i], b[j], acc[i][j]);
        }
        __syncthreads();
    }

    #pragma unroll
    for (int i = 0; i < 8; ++i) {
        const int row = bm * BM + ty * 4 + (i & 3) + 64 * (i >> 2);
        #pragma unroll
        for (int j = 0; j < 8; ++j) {
            const int col = bn * BN + tx * 4 + (j & 3) + 64 * (j >> 2);
            atomicAdd(&C[(size_t)row * NCOLS + col], acc[i][j]);
        }
    }
}

// ---- fused bias + mask + student-t + argmax (unchanged, verified) ----
#define RPB 8

__global__ __launch_bounds__(256, 1)
void student_t_kernel(float* __restrict__ zbuf,
                      const int* __restrict__ mask,
                      const float* __restrict__ b_emb,
                      const float* __restrict__ cent,
                      float* __restrict__ s_out,
                      float* __restrict__ c_out)
{
    __shared__ float cs[50][257];
    __shared__ float zs[RPB][256];
    __shared__ float stbuf[RPB][128];
    __shared__ float c2[NCLU];
    __shared__ float z2s[RPB];
    __shared__ float redbuf[4];
    __shared__ float r_sum, r_idx;

    const int t    = threadIdx.x;
    const int wid  = t >> 6;
    const int lane = t & 63;
    const int row0 = blockIdx.x * RPB;

    const float bt = b_emb[t];

    if (t >= 100 && t < 128) {
        #pragma unroll
        for (int r = 0; r < RPB; ++r) stbuf[r][t] = 0.f;
    }

    for (int r = 0; r < RPB; ++r) {
        const int row = row0 + r;
        const float z = zbuf[(size_t)row * NCOLS + t] + bt;
        const bool m = mask[row] != 0;
        zbuf[(size_t)row * NCOLS + t] = m ? z : 0.f;
        zs[r][t] = z;
        float v = z * z;
        #pragma unroll
        for (int off = 32; off > 0; off >>= 1) v += __shfl_down(v, off, 64);
        if (lane == 0) redbuf[wid] = v;
        __syncthreads();
        if (t == 0) z2s[r] = redbuf[0] + redbuf[1] + redbuf[2] + redbuf[3];
        __syncthreads();
    }

    for (int ch = 0; ch < 2; ++ch) {
        const int kbase = ch * 50;
        for (int i = t; i < 50 * 256; i += 256) {
            const int k = i >> 8;
            const int d = i & 255;
            cs[k][d] = cent[(size_t)(kbase + k) * 256 + d];
        }
        __syncthreads();
        if (t < 50) {
            float s = 0.f;
            for (int d = 0; d < 256; ++d) s = fmaf(cs[t][d], cs[t][d], s);
            c2[kbase + t] = s;
        }
        __syncthreads();
        for (int rp = 0; rp < RPB / 2; ++rp) {
            if (t < 100) {
                const int r = rp * 2 + t / 50;
                const int k = t % 50;
                float dot = 0.f;
                for (int d = 0; d < 256; ++d)
                    dot = fmaf(zs[r][d], cs[k][d], dot);
                const float d2   = z2s[r] + c2[kbase + k] - 2.f * dot;
                const float dist = sqrtf(fmaxf(d2, 0.f));
                stbuf[r][kbase + k] = 1.f / (1.f + dist);
            }
        }
        __syncthreads();
    }

    for (int r = 0; r < RPB; ++r) {
        const int row = row0 + r;
        if (wid == 0) {
            const float v1 = stbuf[r][lane];
            const float v2 = stbuf[r][lane + 64];
            float sv = v1 + v2;
            #pragma unroll
            for (int off = 32; off > 0; off >>= 1) sv += __shfl_down(sv, off, 64);
            float mv; int mi;
            if (v2 > v1) { mv = v2; mi = lane + 64; } else { mv = v1; mi = lane; }
            #pragma unroll
            for (int off = 32; off > 0; off >>= 1) {
                const float ov = __shfl_down(mv, off, 64);
                const int   oi = __shfl_down(mi, off, 64);
                if (ov > mv || (ov == mv && oi < mi)) { mv = ov; mi = oi; }
            }
            if (lane == 0) { r_sum = sv; r_idx = (float)mi; }
        }
        __syncthreads();
        const bool m = mask[row] != 0;
        if (t < NCLU) s_out[(size_t)row * NCLU + t] = m ? stbuf[r][t] / r_sum : 0.f;
        if (t == 0)   c_out[row] = m ? r_idx : 0.f;
        __syncthreads();
    }
}

extern "C" void kernel_launch(void* const* d_in, const int* in_sizes, int n_in,
                              void* d_out, int out_size, void* d_ws, size_t ws_size,
                              hipStream_t stream)
{
    const float* z_roi = (const float*)d_in[0];
    const int*   mask  = (const int*)d_in[1];
    const float* w_emb = (const float*)d_in[2];
    const float* b_emb = (const float*)d_in[3];
    const float* cent  = (const float*)d_in[4];

    float* out   = (float*)d_out;
    float* z_all = out;
    float* s_out = out + (size_t)MROWS * NCOLS;
    float* c_out = s_out + (size_t)MROWS * NCLU;

    // zero the split-K accumulator region (d_out is poisoned every launch)
    hipMemsetAsync(z_all, 0, (size_t)MROWS * NCOLS * sizeof(float), stream);

    const size_t ws_need = (size_t)2 * SPLITK * NSTEP * BTILE;   // 64 MB swizzled B stream

    if (ws_size >= ws_need) {
        unsigned char* bws = (unsigned char*)d_ws;
        prep_b_kernel<<<dim3(NSTEP, SPLITK, 2), 256, 0, stream>>>(w_emb, bws);
        gemm_mfma_kernel<<<dim3(MROWS / BMT, NCOLS / BNT, SPLITK), 256, 0, stream>>>(
            z_roi, bws, z_all);
    } else {
        gemm_splitk_kernel<<<dim3(MROWS / BM, NCOLS / BN, SPLITK), 256, 0, stream>>>(
            z_roi, w_emb, z_all);
    }

    student_t_kernel<<<dim3(MROWS / RPB), 256, 0, stream>>>(z_all, mask, b_emb, cent,
                                                            s_out, c_out);
}

// Round 4
// 960.184 us; speedup vs baseline: 1.0610x; 1.0610x over previous
//
#include <hip/hip_runtime.h>
#include <math.h>

// Problem constants
#define MROWS 2048      // BN*SN = 32*64
#define NCOLS 256       // NDF
#define KDIM  65536     // IN_DIM
#define NCLU  100

// ---- legacy (fallback) GEMM config ----
#define BM 128
#define BN 128
#define BK 32
#define SPLITK 16
#define KCHUNK (KDIM / SPLITK)   // 4096
#define SA 132
#define SB 128

// ---- MFMA GEMM config ----
#define BMT 128
#define BNT 128
#define BKT 32
#define NSTEP (KCHUNK / BKT)     // 128 k-steps per block
#define BTILE 16384              // bytes per B k-step tile: 128 n-rows x 128 B (hi|lo, XOR-swizzled)

typedef _Float16 half8  __attribute__((ext_vector_type(8)));
typedef float    f32x4  __attribute__((ext_vector_type(4)));

// global_load_lds: LDS dest = wave-uniform base + lane*16 (linear); global src per-lane.
#define GLD_LDS16(g, l) __builtin_amdgcn_global_load_lds(                      \
    (__attribute__((address_space(1))) void*)(g),                              \
    (__attribute__((address_space(3))) void*)(l), 16, 0, 0)

// ------------------------------------------------------------------
// Prepass (verified R3, absmax 0.125): B [K][256] fp32 -> swizzled-tiled
// hi/lo f16 stream. Tile T = ((bn*16 + ks)*128 + step), 16 KB each:
//   byte (n, x): logical lx = x ^ ((n&7)<<4); lx<64 -> hi, lx>=64 -> lo.
// ------------------------------------------------------------------
__global__ __launch_bounds__(256, 4)
void prep_b_kernel(const float* __restrict__ B, unsigned char* __restrict__ Bws)
{
    __shared__ float Ts[BKT][132];   // [k][n], +4 pad
    const int t    = threadIdx.x;
    const int step = blockIdx.x;
    const int ks   = blockIdx.y;
    const int bnb  = blockIdx.z;

    const int kbase = ks * KCHUNK + step * BKT;
    const int nbase = bnb * 128;

    #pragma unroll
    for (int r = 0; r < 4; ++r) {
        const int fidx = r * 256 + t;
        const int k  = fidx >> 5;        // 0..31
        const int c4 = fidx & 31;        // float4 col
        const float4 v = *(const float4*)(B + (size_t)(kbase + k) * NCOLS + nbase + c4 * 4);
        *(float4*)&Ts[k][c4 * 4] = v;
    }
    __syncthreads();

    unsigned char* outT = Bws + (size_t)((bnb * SPLITK + ks) * NSTEP + step) * BTILE;
    #pragma unroll
    for (int r = 0; r < 4; ++r) {
        const int oidx = r * 256 + t;
        const int n  = oidx >> 3;        // 0..127
        const int X  = oidx & 7;         // 16-B block within row
        const int LX = X ^ (n & 7);      // logical block
        const int mtx = LX >> 2;         // 0 = hi, 1 = lo
        const int kb  = (LX & 3) * 8;    // k offset of this 8-half block
        half8 hv;
        #pragma unroll
        for (int j = 0; j < 8; ++j) {
            const float v = Ts[kb + j][n];
            const _Float16 h = (_Float16)v;            // RNE
            hv[j] = mtx ? (_Float16)(v - (float)h) : h;
        }
        *(half8*)(outT + n * 128 + X * 16) = hv;       // coalesced: 8 lanes = 1 row
    }
}

// ------------------------------------------------------------------
// MFMA split-K GEMM v3: counted-vmcnt pipeline (T3+T4).
//  - A: global -> reg (per-wave own fragments), cvt f16 in-reg. No A LDS.
//  - B: 3-deep LDS buffers, global_load_lds issued 2 steps ahead.
//  - Main loop never drains vmcnt to 0: per step
//      issue(s+2) -> ds_read B(s) -> 32 MFMA -> cvt A(s+1)[compiler-counted
//      vmcnt] -> asm vmcnt(12) [retires B(s+1) only] -> s_barrier.
// ------------------------------------------------------------------
__global__ __launch_bounds__(256, 2)
void gemm_mfma_kernel(const float* __restrict__ A,
                      const unsigned char* __restrict__ Bws,
                      float* __restrict__ C)
{
    __shared__ __align__(16) unsigned char Bs[3][BTILE];   // 48 KB -> 2 blocks/CU

    const int t    = threadIdx.x;
    const int lane = t & 63;
    const int wid  = t >> 6;
    const int wm   = wid >> 1;      // 0..1  (m-half of the 128x128 tile)
    const int wn   = wid & 1;       // 0..1  (n-half)

    const int bm  = blockIdx.x;
    const int bnb = blockIdx.y;
    const int ks  = blockIdx.z;

    const float* Ab = A + (size_t)bm * BMT * KDIM + (size_t)ks * KCHUNK;
    const unsigned char* Bb = Bws + (size_t)((bnb * SPLITK + ks) * NSTEP) * BTILE;

    const int r16  = lane & 15;
    const int kb16 = lane >> 4;      // k-block 0..3 (8 halves each)

    // per-lane A row pointers: row = wm*64 + mf*16 + r16, k-offset kb16*8
    const float* Arow[4];
    #pragma unroll
    for (int mf = 0; mf < 4; ++mf)
        Arow[mf] = Ab + (size_t)(wm * 64 + mf * 16 + r16) * KDIM + kb16 * 8;

    // B frag byte offsets within a tile (hi at logical bytes [0,64), lo [64,128))
    int bhoff[4], bloff[4];
    #pragma unroll
    for (int nf = 0; nf < 4; ++nf) {
        const int n    = wn * 64 + nf * 16 + r16;
        const int mask = (n & 7) << 4;
        bhoff[nf] = n * 128 + ((kb16 * 16) ^ mask);
        bloff[nf] = n * 128 + ((64 + kb16 * 16) ^ mask);
    }

    f32x4 acc[4][4] = {};
    float4 pA0[8], pA1[8];           // two raw-A banks (steps s, s+1 in flight)
    half8  av0[4], av1[4];           // cvt'd A fragments (current / next)

    // rotating B-buffer pointers: b0 = step s, b1 = s+1, b2 = s+2 (gld target)
    unsigned char* b0 = &Bs[0][0];
    unsigned char* b1 = &Bs[1][0];
    unsigned char* b2 = &Bs[2][0];

    // ---- prologue: issue steps 0 and 1 ----
    #pragma unroll
    for (int mf = 0; mf < 4; ++mf) {
        pA0[2 * mf]     = *(const float4*)(Arow[mf] + 0);
        pA0[2 * mf + 1] = *(const float4*)(Arow[mf] + 4);
    }
    #pragma unroll
    for (int r = 0; r < 4; ++r)
        GLD_LDS16(Bb + (size_t)(r * 256 + t) * 16, b0 + (r * 256 + wid * 64) * 16);
    #pragma unroll
    for (int mf = 0; mf < 4; ++mf) {
        pA1[2 * mf]     = *(const float4*)(Arow[mf] + BKT + 0);
        pA1[2 * mf + 1] = *(const float4*)(Arow[mf] + BKT + 4);
    }
    {
        const unsigned char* Bt = Bb + (size_t)1 * BTILE;
        #pragma unroll
        for (int r = 0; r < 4; ++r)
            GLD_LDS16(Bt + (size_t)(r * 256 + t) * 16, b1 + (r * 256 + wid * 64) * 16);
    }
    // cvt A(0) -> av0 (compiler inserts exact counted vmcnt for pA0 dependency)
    #pragma unroll
    for (int mf = 0; mf < 4; ++mf) {
        half8 h;
        h[0] = (_Float16)pA0[2 * mf].x;     h[1] = (_Float16)pA0[2 * mf].y;
        h[2] = (_Float16)pA0[2 * mf].z;     h[3] = (_Float16)pA0[2 * mf].w;
        h[4] = (_Float16)pA0[2 * mf + 1].x; h[5] = (_Float16)pA0[2 * mf + 1].y;
        h[6] = (_Float16)pA0[2 * mf + 1].z; h[7] = (_Float16)pA0[2 * mf + 1].w;
        av0[mf] = h;
    }
    asm volatile("s_waitcnt vmcnt(12)" ::: "memory");   // B(0) deposited; A(1),B(1) in flight
    __builtin_amdgcn_s_barrier();
    __builtin_amdgcn_sched_barrier(0);

    // step body: compute step S (frags AC, B in b0); prefetch S+2 raw into PF;
    // cvt raw PC (=A(S+1)) into AN; counted-wait B(S+1); barrier; rotate.
    auto STEP = [&](int S, float4 (&PF)[8], float4 (&PC)[8],
                    half8 (&AC)[4], half8 (&AN)[4]) {
        if (S + 2 < NSTEP) {
            const int kk2 = (S + 2) * BKT;
            #pragma unroll
            for (int mf = 0; mf < 4; ++mf) {
                PF[2 * mf]     = *(const float4*)(Arow[mf] + kk2 + 0);
                PF[2 * mf + 1] = *(const float4*)(Arow[mf] + kk2 + 4);
            }
            const unsigned char* Bt = Bb + (size_t)(S + 2) * BTILE;
            #pragma unroll
            for (int r = 0; r < 4; ++r)
                GLD_LDS16(Bt + (size_t)(r * 256 + t) * 16,
                          b2 + (r * 256 + wid * 64) * 16);
        }

        half8 bh[4], bl[4];
        #pragma unroll
        for (int nf = 0; nf < 4; ++nf) {
            bh[nf] = *(const half8*)(b0 + bhoff[nf]);
            bl[nf] = *(const half8*)(b0 + bloff[nf]);
        }
        #pragma unroll
        for (int mf = 0; mf < 4; ++mf)
            #pragma unroll
            for (int nf = 0; nf < 4; ++nf) {
                acc[mf][nf] = __builtin_amdgcn_mfma_f32_16x16x32_f16(AC[mf], bh[nf], acc[mf][nf], 0, 0, 0);
                acc[mf][nf] = __builtin_amdgcn_mfma_f32_16x16x32_f16(AC[mf], bl[nf], acc[mf][nf], 0, 0, 0);
            }

        if (S + 1 < NSTEP) {
            #pragma unroll
            for (int mf = 0; mf < 4; ++mf) {
                half8 h;
                h[0] = (_Float16)PC[2 * mf].x;     h[1] = (_Float16)PC[2 * mf].y;
                h[2] = (_Float16)PC[2 * mf].z;     h[3] = (_Float16)PC[2 * mf].w;
                h[4] = (_Float16)PC[2 * mf + 1].x; h[5] = (_Float16)PC[2 * mf + 1].y;
                h[6] = (_Float16)PC[2 * mf + 1].z; h[7] = (_Float16)PC[2 * mf + 1].w;
                AN[mf] = h;
            }
            // oldest outstanding are B(S+1)x4 (all current-step issues are younger):
            // vmcnt(12) retires them; never drains the S+2 pipeline.
            if (S + 2 < NSTEP) asm volatile("s_waitcnt vmcnt(12)" ::: "memory");
            else               asm volatile("s_waitcnt vmcnt(0)"  ::: "memory");
        }
        __builtin_amdgcn_s_barrier();
        __builtin_amdgcn_sched_barrier(0);
        unsigned char* tmp = b0; b0 = b1; b1 = b2; b2 = tmp;
    };

    for (int s = 0; s < NSTEP; s += 2) {
        STEP(s,     pA0, pA1, av0, av1);
        STEP(s + 1, pA1, pA0, av1, av0);
    }

    // epilogue: C/D layout col=lane&15, row=4*(lane>>4)+reg (m89-verified)
    const int row0 = bm * BMT + wm * 64 + (lane >> 4) * 4;
    const int col0 = bnb * BNT + wn * 64 + r16;
    #pragma unroll
    for (int mf = 0; mf < 4; ++mf)
        #pragma unroll
        for (int nf = 0; nf < 4; ++nf)
            #pragma unroll
            for (int r = 0; r < 4; ++r)
                atomicAdd(&C[(size_t)(row0 + mf * 16 + r) * NCOLS + col0 + nf * 16],
                          acc[mf][nf][r]);
}

// ------------------------------------------------------------------
// Fallback vector-FMA GEMM (verified baseline) — used only if ws too small
// ------------------------------------------------------------------
__global__ __launch_bounds__(256, 2)
void gemm_splitk_kernel(const float* __restrict__ A, const float* __restrict__ B,
                        float* __restrict__ C)
{
    __shared__ float As[BK][SA];
    __shared__ float Bs[BK][SB];

    const int t  = threadIdx.x;
    const int tx = t & 15;
    const int ty = t >> 4;

    const int bm = blockIdx.x;
    const int bn = blockIdx.y;
    const int bs = blockIdx.z;

    const float* Ab = A + (size_t)bm * BM * KDIM + (size_t)bs * KCHUNK;
    const float* Bb = B + (size_t)bs * KCHUNK * NCOLS + bn * BN;

    const int arow = t >> 3;
    const int akf4 = t & 7;
    const int bkr  = t >> 5;
    const int bnf4 = t & 31;

    float acc[8][8];
    #pragma unroll
    for (int i = 0; i < 8; ++i)
        #pragma unroll
        for (int j = 0; j < 8; ++j) acc[i][j] = 0.f;

    for (int kk = 0; kk < KCHUNK; kk += BK) {
        #pragma unroll
        for (int i = 0; i < 4; ++i) {
            const int r = arow + 32 * i;
            const float4 v = *(const float4*)(Ab + (size_t)r * KDIM + kk + akf4 * 4);
            As[akf4 * 4 + 0][r] = v.x;
            As[akf4 * 4 + 1][r] = v.y;
            As[akf4 * 4 + 2][r] = v.z;
            As[akf4 * 4 + 3][r] = v.w;
        }
        #pragma unroll
        for (int i = 0; i < 4; ++i) {
            const int r = bkr + 8 * i;
            *(float4*)&Bs[r][bnf4 * 4] =
                *(const float4*)(Bb + (size_t)(kk + r) * NCOLS + bnf4 * 4);
        }
        __syncthreads();

        #pragma unroll 8
        for (int k = 0; k < BK; ++k) {
            float a[8], b[8];
            *(float4*)&a[0] = *(const float4*)&As[k][ty * 4];
            *(float4*)&a[4] = *(const float4*)&As[k][64 + ty * 4];
            *(float4*)&b[0] = *(const float4*)&Bs[k][tx * 4];
            *(float4*)&b[4] = *(const float4*)&Bs[k][64 + tx * 4];
            #pragma unroll
            for (int i = 0; i < 8; ++i)
                #pragma unroll
                for (int j = 0; j < 8; ++j)
                    acc[i][j] = fmaf(a[i], b[j], acc[i][j]);
        }
        __syncthreads();
    }

    #pragma unroll
    for (int i = 0; i < 8; ++i) {
        const int row = bm * BM + ty * 4 + (i & 3) + 64 * (i >> 2);
        #pragma unroll
        for (int j = 0; j < 8; ++j) {
            const int col = bn * BN + tx * 4 + (j & 3) + 64 * (j >> 2);
            atomicAdd(&C[(size_t)row * NCOLS + col], acc[i][j]);
        }
    }
}

// ---- fused bias + mask + student-t + argmax (unchanged, verified) ----
#define RPB 8

__global__ __launch_bounds__(256, 1)
void student_t_kernel(float* __restrict__ zbuf,
                      const int* __restrict__ mask,
                      const float* __restrict__ b_emb,
                      const float* __restrict__ cent,
                      float* __restrict__ s_out,
                      float* __restrict__ c_out)
{
    __shared__ float cs[50][257];
    __shared__ float zs[RPB][256];
    __shared__ float stbuf[RPB][128];
    __shared__ float c2[NCLU];
    __shared__ float z2s[RPB];
    __shared__ float redbuf[4];
    __shared__ float r_sum, r_idx;

    const int t    = threadIdx.x;
    const int wid  = t >> 6;
    const int lane = t & 63;
    const int row0 = blockIdx.x * RPB;

    const float bt = b_emb[t];

    if (t >= 100 && t < 128) {
        #pragma unroll
        for (int r = 0; r < RPB; ++r) stbuf[r][t] = 0.f;
    }

    for (int r = 0; r < RPB; ++r) {
        const int row = row0 + r;
        const float z = zbuf[(size_t)row * NCOLS + t] + bt;
        const bool m = mask[row] != 0;
        zbuf[(size_t)row * NCOLS + t] = m ? z : 0.f;
        zs[r][t] = z;
        float v = z * z;
        #pragma unroll
        for (int off = 32; off > 0; off >>= 1) v += __shfl_down(v, off, 64);
        if (lane == 0) redbuf[wid] = v;
        __syncthreads();
        if (t == 0) z2s[r] = redbuf[0] + redbuf[1] + redbuf[2] + redbuf[3];
        __syncthreads();
    }

    for (int ch = 0; ch < 2; ++ch) {
        const int kbase = ch * 50;
        for (int i = t; i < 50 * 256; i += 256) {
            const int k = i >> 8;
            const int d = i & 255;
            cs[k][d] = cent[(size_t)(kbase + k) * 256 + d];
        }
        __syncthreads();
        if (t < 50) {
            float s = 0.f;
            for (int d = 0; d < 256; ++d) s = fmaf(cs[t][d], cs[t][d], s);
            c2[kbase + t] = s;
        }
        __syncthreads();
        for (int rp = 0; rp < RPB / 2; ++rp) {
            if (t < 100) {
                const int r = rp * 2 + t / 50;
                const int k = t % 50;
                float dot = 0.f;
                for (int d = 0; d < 256; ++d)
                    dot = fmaf(zs[r][d], cs[k][d], dot);
                const float d2   = z2s[r] + c2[kbase + k] - 2.f * dot;
                const float dist = sqrtf(fmaxf(d2, 0.f));
                stbuf[r][kbase + k] = 1.f / (1.f + dist);
            }
        }
        __syncthreads();
    }

    for (int r = 0; r < RPB; ++r) {
        const int row = row0 + r;
        if (wid == 0) {
            const float v1 = stbuf[r][lane];
            const float v2 = stbuf[r][lane + 64];
            float sv = v1 + v2;
            #pragma unroll
            for (int off = 32; off > 0; off >>= 1) sv += __shfl_down(sv, off, 64);
            float mv; int mi;
            if (v2 > v1) { mv = v2; mi = lane + 64; } else { mv = v1; mi = lane; }
            #pragma unroll
            for (int off = 32; off > 0; off >>= 1) {
                const float ov = __shfl_down(mv, off, 64);
                const int   oi = __shfl_down(mi, off, 64);
                if (ov > mv || (ov == mv && oi < mi)) { mv = ov; mi = oi; }
            }
            if (lane == 0) { r_sum = sv; r_idx = (float)mi; }
        }
        __syncthreads();
        const bool m = mask[row] != 0;
        if (t < NCLU) s_out[(size_t)row * NCLU + t] = m ? stbuf[r][t] / r_sum : 0.f;
        if (t == 0)   c_out[row] = m ? r_idx : 0.f;
        __syncthreads();
    }
}

extern "C" void kernel_launch(void* const* d_in, const int* in_sizes, int n_in,
                              void* d_out, int out_size, void* d_ws, size_t ws_size,
                              hipStream_t stream)
{
    const float* z_roi = (const float*)d_in[0];
    const int*   mask  = (const int*)d_in[1];
    const float* w_emb = (const float*)d_in[2];
    const float* b_emb = (const float*)d_in[3];
    const float* cent  = (const float*)d_in[4];

    float* out   = (float*)d_out;
    float* z_all = out;
    float* s_out = out + (size_t)MROWS * NCOLS;
    float* c_out = s_out + (size_t)MROWS * NCLU;

    // zero the split-K accumulator region (d_out is poisoned every launch)
    hipMemsetAsync(z_all, 0, (size_t)MROWS * NCOLS * sizeof(float), stream);

    const size_t ws_need = (size_t)2 * SPLITK * NSTEP * BTILE;   // 64 MB swizzled B stream

    if (ws_size >= ws_need) {
        unsigned char* bws = (unsigned char*)d_ws;
        prep_b_kernel<<<dim3(NSTEP, SPLITK, 2), 256, 0, stream>>>(w_emb, bws);
        gemm_mfma_kernel<<<dim3(MROWS / BMT, NCOLS / BNT, SPLITK), 256, 0, stream>>>(
            z_roi, bws, z_all);
    } else {
        gemm_splitk_kernel<<<dim3(MROWS / BM, NCOLS / BN, SPLITK), 256, 0, stream>>>(
            z_roi, w_emb, z_all);
    }

    student_t_kernel<<<dim3(MROWS / RPB), 256, 0, stream>>>(z_all, mask, b_emb, cent,
                                                            s_out, c_out);
}